// Round 16
// baseline (501.315 us; speedup 1.0000x reference)
//
#include <hip/hip_runtime.h>
#include <stdint.h>
#include <math.h>

// ---------------------------------------------------------------------------
// DecoderRNN: 2-layer LSTM (B=32, T=64, E=H=512) + vocab projection (V=50257)
//
//   FUSED kernel: blocks 0..63  = split-K persistent LSTM (round-9 structure)
//                 blocks 64..   = logits-GEMM tiles (128x128xBK64), poll-gated
//                 on h1 readiness; row (b,t) uses h1[t+1].
//   Round-16: (a) LSTM branch runs at s_setprio(1) -- producer waves win
//   issue arbitration over GEMM co-residents (reduce recurrence stretch);
//   (b) GEMM B-panel double-buffered (B[kt+1] in flight during compute of kt)
//   to hide HBM latency; (c) nt out-stores kept.
// ---------------------------------------------------------------------------

typedef unsigned short u16;
typedef __bf16 bf16x8 __attribute__((ext_vector_type(8)));
typedef float  f32x4  __attribute__((ext_vector_type(4)));

#define BATCH   32
#define SEQT    64
#define NSTEP   65
#define EMB     512
#define HID     512
#define VOCAB   50257
#define VPADG   51200         // 400*128, zero-padded
#define NWG_LSTM 64
#define NT_TILES 400
#define MT_TILES 16           // 2048/128

static __device__ __forceinline__ u16 f2bf(float f) {
  unsigned u = __float_as_uint(f);
  u += 0x7FFFu + ((u >> 16) & 1u);
  return (u16)(u >> 16);
}

static __device__ __forceinline__ bf16x8 ld_frag(const u16* p16) {
  union { uint4 u; bf16x8 v; } f;
  f.u = *(const uint4*)p16;
  return f.v;
}

// asm 16B loads: result valid only after manual s_waitcnt vmcnt + sched_barrier.
static __device__ __forceinline__ void gload16(uint4* dst, const void* p) {
  asm volatile("global_load_dwordx4 %0, %1, off" : "=v"(*dst) : "v"(p));
}
static __device__ __forceinline__ void gload16_sys(uint4* dst, const void* p) {
  asm volatile("global_load_dwordx4 %0, %1, off sc0 sc1" : "=v"(*dst) : "v"(p));
}
static __device__ __forceinline__ void st_exch32(void* p, unsigned v) {
  (void)__hip_atomic_exchange((unsigned*)p, v, __ATOMIC_RELAXED,
                              __HIP_MEMORY_SCOPE_AGENT);
}
// non-temporal f32 store (output is write-once, never read)
static __device__ __forceinline__ void st_nt(float* p, float v) {
  asm volatile("global_store_dword %0, %1, off nt" :: "v"(p), "v"(v) : "memory");
}

static __device__ __forceinline__ float sigmoid_fast(float x) {
  return 1.0f / (1.0f + __expf(-x));
}
static __device__ __forceinline__ float tanh_fast(float x) {
  return 1.0f - 2.0f / (__expf(2.0f * x) + 1.0f);
}

// LSTM poll: latency-critical, tight loop
static __device__ __forceinline__ void wave_poll(const unsigned* slots,
                                                 int base_slot, unsigned tgt,
                                                 int lane) {
  const unsigned* p = slots + (base_slot + (lane & 31)) * 16;
  for (;;) {
    unsigned v = __hip_atomic_load(p, __ATOMIC_RELAXED, __HIP_MEMORY_SCOPE_AGENT);
    if (__all((int)(v >= tgt))) break;
    __builtin_amdgcn_s_sleep(1);
  }
}

// GEMM poll: throughput-path, coarse backoff
static __device__ __forceinline__ void wave_poll_slow(const unsigned* slots,
                                                      int base_slot, unsigned tgt,
                                                      int lane) {
  const unsigned* p = slots + (base_slot + (lane & 31)) * 16;
  for (;;) {
    unsigned v = __hip_atomic_load(p, __ATOMIC_RELAXED, __HIP_MEMORY_SCOPE_AGENT);
    if (__all((int)(v >= tgt))) break;
    __builtin_amdgcn_s_sleep(32);
  }
}

#define WAITVM(N) do { asm volatile("s_waitcnt vmcnt(" #N ")" ::: "memory"); \
                       __builtin_amdgcn_sched_barrier(0); } while (0)

// ---------------------------------------------------------------------------
// K1: compact layout dst[t][e>>4][b][e&15]
// ---------------------------------------------------------------------------
__global__ void build_inputs(const float* __restrict__ features,
                             const int*   __restrict__ captions,
                             const float* __restrict__ embed_w,
                             u16* __restrict__ dst) {
  int idx = blockIdx.x * blockDim.x + threadIdx.x;
  const int n = NSTEP * BATCH * EMB;
  if (idx >= n) return;
  int e = idx & (EMB - 1);
  int rem = idx >> 9;
  int b = rem & (BATCH - 1);
  int t = rem >> 5;
  float v;
  if (t == 0) v = features[b * EMB + e];
  else        v = embed_w[(size_t)captions[b * SEQT + (t - 1)] * EMB + e];
  dst[(size_t)t * 16384 + (e >> 4) * 512 + b * 16 + (e & 15)] = f2bf(v);
}

// ---------------------------------------------------------------------------
// K2
// ---------------------------------------------------------------------------
__global__ void cast_bf16(const float* __restrict__ src, u16* __restrict__ dst, int n4) {
  int i = blockIdx.x * blockDim.x + threadIdx.x;
  if (i >= n4) return;
  float4 v = ((const float4*)src)[i];
  ushort4 o;
  o.x = f2bf(v.x); o.y = f2bf(v.y); o.z = f2bf(v.z); o.w = f2bf(v.w);
  ((ushort4*)dst)[i] = o;
}

__global__ void cast_pad_wout(const float* __restrict__ src, u16* __restrict__ dst) {
  int i = blockIdx.x * blockDim.x + threadIdx.x;
  const int n4 = VPADG * 512 / 4;
  const int nsrc4 = VOCAB * 512 / 4;
  if (i >= n4) return;
  ushort4 o;
  if (i < nsrc4) {
    float4 v = ((const float4*)src)[i];
    o.x = f2bf(v.x); o.y = f2bf(v.y); o.z = f2bf(v.z); o.w = f2bf(v.w);
  } else {
    o.x = 0; o.y = 0; o.z = 0; o.w = 0;
  }
  ((ushort4*)dst)[i] = o;
}

// ---------------------------------------------------------------------------
// FUSED kernel
// ---------------------------------------------------------------------------
__global__ __launch_bounds__(256, 1)
void fused_lstm_logits(const u16* __restrict__ inputs_bf,   // [t][32sl][32b][16]
                       const u16* __restrict__ wih0, const u16* __restrict__ whh0,
                       const float* __restrict__ b0,
                       const u16* __restrict__ wih1, const u16* __restrict__ whh1,
                       const float* __restrict__ b1,
                       u16* h0_all, u16* h1_all,             // [t][32sl][32b][16]
                       const u16* __restrict__ Bg,           // w_out bf16 [51200][512]
                       const float* __restrict__ b_out,
                       float* __restrict__ out,
                       unsigned* slots) {
  __shared__ char smem[49152];
  const int tid  = threadIdx.x;
  const int lane = tid & 63;
  const int wv   = tid >> 6;
  const int l15  = lane & 15;
  const int lg   = lane >> 4;

  if (blockIdx.x < NWG_LSTM) {
    // =================== LSTM part (round-9 structure) ===================
    __builtin_amdgcn_s_setprio(1);     // producer waves win CU arbitration
    const int wg    = blockIdx.x;
    const int layer = wg >> 5;
    const int jsl   = wg & 31;
    const int j0    = jsl * 16;
    const bool is_h = (wv >= 2);
    const int  wq   = wv & 1;

    const u16*   wih  = layer ? wih1 : wih0;
    const u16*   whh  = layer ? whh1 : whh0;
    const float* bias = layer ? b1 : b0;
    const char* xsrc0 = (const char*)(layer ? h0_all : inputs_bf);
    const char* hsrc0 = (const char*)(layer ? h1_all : h0_all);
    u16*        hdst  = layer ? h1_all : h0_all;
    const int own_base = layer ? 32 : 0;

    float* gparts = (float*)smem;              // [w][g][512] = 32 KB
    float* bias_l = (float*)(smem + 32768);    // [64]

    if (tid < 64) bias_l[tid] = bias[(tid >> 4) * HID + j0 + (tid & 15)];

    uint4 wreg[8][4];
    {
      const u16* wmat = is_h ? whh : wih;
      const int  kb   = wq * 256;
#pragma unroll
      for (int kc = 0; kc < 8; ++kc) {
#pragma unroll
        for (int g4 = 0; g4 < 4; ++g4) {
          gload16(&wreg[kc][g4],
                  wmat + (size_t)(g4 * 512 + j0 + l15) * 512 + kb + kc * 32 + 8 * lg);
        }
        WAITVM(0);
      }
    }
    __syncthreads();

    const int laoff = wq * 16384 + (lg >> 1) * 1024 + l15 * 32 + (lg & 1) * 16;
    const int pw_b  = tid >> 3;
    const int pw_jq = (tid * 2) & 15;
    float creg[2] = {0.f, 0.f};

    for (int t = 0; t < NSTEP; ++t) {
      f32x4 acc[2][4];
#pragma unroll
      for (int bh = 0; bh < 2; ++bh)
#pragma unroll
        for (int g4 = 0; g4 < 4; ++g4) acc[bh][g4] = (f32x4){0.f, 0.f, 0.f, 0.f};

      const bool have_a = is_h ? (t > 0) : true;
      if (have_a) {
        const char* src;
        bool sys;
        if (!is_h) {
          src = xsrc0 + (size_t)t * 32768;
          sys = (layer == 1);
          if (layer == 1) wave_poll(slots, 0, (unsigned)(t + 1), lane);
        } else {
          src = hsrc0 + (size_t)(t - 1) * 32768;
          sys = true;
          wave_poll(slots, own_base, (unsigned)t, lane);
        }
        uint4 areg[2][8];
        if (sys) {
#pragma unroll
          for (int kc = 0; kc < 8; ++kc) gload16_sys(&areg[0][kc], src + laoff + kc * 2048);
#pragma unroll
          for (int kc = 0; kc < 8; ++kc) gload16_sys(&areg[1][kc], src + laoff + kc * 2048 + 512);
        } else {
#pragma unroll
          for (int kc = 0; kc < 8; ++kc) gload16(&areg[0][kc], src + laoff + kc * 2048);
#pragma unroll
          for (int kc = 0; kc < 8; ++kc) gload16(&areg[1][kc], src + laoff + kc * 2048 + 512);
        }
        WAITVM(8);
#pragma unroll
        for (int kc = 0; kc < 8; ++kc)
#pragma unroll
          for (int g4 = 0; g4 < 4; ++g4)
            acc[0][g4] = __builtin_amdgcn_mfma_f32_16x16x32_bf16(
                *(const bf16x8*)&areg[0][kc], *(const bf16x8*)&wreg[kc][g4],
                acc[0][g4], 0, 0, 0);
        WAITVM(0);
#pragma unroll
        for (int kc = 0; kc < 8; ++kc)
#pragma unroll
          for (int g4 = 0; g4 < 4; ++g4)
            acc[1][g4] = __builtin_amdgcn_mfma_f32_16x16x32_bf16(
                *(const bf16x8*)&areg[1][kc], *(const bf16x8*)&wreg[kc][g4],
                acc[1][g4], 0, 0, 0);
      }
#pragma unroll
      for (int bh = 0; bh < 2; ++bh)
#pragma unroll
        for (int g4 = 0; g4 < 4; ++g4)
#pragma unroll
          for (int rr = 0; rr < 4; ++rr)
            gparts[(wv * 4 + g4) * 512 + (bh * 16 + 4 * lg + rr) * 16 + l15] = acc[bh][g4][rr];
      __syncthreads();

      {
        const int b = pw_b, jq = pw_jq;
        float hv[2];
#pragma unroll
        for (int u = 0; u < 2; ++u) {
          const int jj = jq + u;
          float gi = bias_l[0 * 16 + jj];
          float gf = bias_l[1 * 16 + jj];
          float gg = bias_l[2 * 16 + jj];
          float go = bias_l[3 * 16 + jj];
#pragma unroll
          for (int w = 0; w < 4; ++w) {
            gi += gparts[(w * 4 + 0) * 512 + b * 16 + jj];
            gf += gparts[(w * 4 + 1) * 512 + b * 16 + jj];
            gg += gparts[(w * 4 + 2) * 512 + b * 16 + jj];
            go += gparts[(w * 4 + 3) * 512 + b * 16 + jj];
          }
          float cn = sigmoid_fast(gf) * creg[u] + sigmoid_fast(gi) * tanh_fast(gg);
          creg[u] = cn;
          hv[u] = sigmoid_fast(go) * tanh_fast(cn);
        }
        unsigned pk32 = (unsigned)f2bf(hv[0]) | ((unsigned)f2bf(hv[1]) << 16);
        st_exch32((char*)hdst + (size_t)t * 32768 + jsl * 1024 + b * 32 + jq * 2, pk32);
      }
      asm volatile("s_waitcnt vmcnt(0)" ::: "memory");   // drain h exchange (L3 ack)
      __syncthreads();
      if (tid == 0)
        (void)__hip_atomic_exchange(&slots[wg * 16], (unsigned)(t + 1),
                                    __ATOMIC_RELAXED, __HIP_MEMORY_SCOPE_AGENT);
    }
    return;
  }

  // =================== GEMM tile part (128x128, B double-buffered) ==========
  // out row (b, t_out) uses h1[t_out + 1]; A row ra = t_out*32 + b.
  const int g  = blockIdx.x - NWG_LSTM;
  const int mt = g / NT_TILES;               // 0..15, readiness-ordered
  const int nt = g - mt * NT_TILES;          // 0..399
  const int m0 = mt * 128, v0 = nt * 128;
  const int wm = (wv & 1) * 64;
  const int wn = (wv >> 1) * 64;

  u16* As = (u16*)smem;                      // 16 KB
  u16* Bs = (u16*)(smem + 16384);            // 2 x 16 KB (double-buffered)
  const char* h1c = (const char*)h1_all;

  f32x4 acc[4][4];
#pragma unroll
  for (int mi = 0; mi < 4; ++mi)
#pragma unroll
    for (int ni = 0; ni < 4; ++ni)
      acc[mi][ni] = (f32x4){0.f, 0.f, 0.f, 0.f};

  const int rswz = (l15 & 7) << 3;

#define A_ISSUE(KT)                                                         \
  _Pragma("unroll")                                                         \
  for (int c = 0; c < 4; ++c) {                                             \
    int chunk = wv * 256 + c * 64 + lane;                                   \
    int row   = chunk >> 3;                                                 \
    int kc3   = (chunk & 7) ^ (row & 7);                                    \
    int gkc   = (KT) * 8 + kc3;                                             \
    int ra    = m0 + row;                                                   \
    const char* pa = h1c + (size_t)((ra >> 5) + 1) * 32768 +                \
                     (gkc >> 1) * 1024 + (ra & 31) * 32 + (gkc & 1) * 16;   \
    u16* la = &As[(wv * 256 + c * 64) * 8];                                 \
    __builtin_amdgcn_global_load_lds(                                       \
        (const __attribute__((address_space(1))) void*)pa,                  \
        (__attribute__((address_space(3))) void*)la, 16, 0, 0);             \
  }

#define B_ISSUE(KT, BUF)                                                    \
  _Pragma("unroll")                                                         \
  for (int c = 0; c < 4; ++c) {                                             \
    int chunk = wv * 256 + c * 64 + lane;                                   \
    int row   = chunk >> 3;                                                 \
    int kcs   = ((chunk & 7) ^ (row & 7)) << 3;                             \
    const u16* gb = Bg + (size_t)(v0 + row) * 512 + (KT) * 64 + kcs;        \
    u16* lb = &Bs[(BUF) * 8192 + (wv * 256 + c * 64) * 8];                  \
    __builtin_amdgcn_global_load_lds(                                       \
        (const __attribute__((address_space(1))) void*)gb,                  \
        (__attribute__((address_space(3))) void*)lb, 16, 0, 0);             \
  }

  // need h1[t_h], t_h in [mt*4+1, mt*4+4] -> all 32 L1 slots >= mt*4+5
  if (tid < 64) wave_poll_slow(slots, 32, (unsigned)(mt * 4 + 5), lane);
  __syncthreads();

  A_ISSUE(0)
  B_ISSUE(0, 0)
  WAITVM(0);
  __syncthreads();

  int cur = 0;
  for (int kt = 0; kt < 8; ++kt) {
    if (kt < 7) B_ISSUE(kt + 1, cur ^ 1)   // next B panel in flight over compute
    const u16* bsrc = &Bs[cur * 8192];
#pragma unroll
    for (int ks = 0; ks < 2; ++ks) {
      bf16x8 af[4], bfr[4];
#pragma unroll
      for (int i = 0; i < 4; ++i) {
        af[i]  = ld_frag(&As[(wm + i * 16 + l15) * 64 + ((ks * 32 + 8 * lg) ^ rswz)]);
        bfr[i] = ld_frag(&bsrc[(wn + i * 16 + l15) * 64 + ((ks * 32 + 8 * lg) ^ rswz)]);
      }
#pragma unroll
      for (int mi = 0; mi < 4; ++mi)
#pragma unroll
        for (int ni = 0; ni < 4; ++ni)
          acc[mi][ni] = __builtin_amdgcn_mfma_f32_16x16x32_bf16(
              af[mi], bfr[ni], acc[mi][ni], 0, 0, 0);
    }
    __syncthreads();                        // all waves done reading As/Bs[cur]
    if (kt < 7) {
      A_ISSUE(kt + 1)                       // As free after barrier
      WAITVM(0);                            // A-next + B-next complete
      __syncthreads();
      cur ^= 1;
    }
  }

  // all-padded tiles (v0 >= VOCAB) produce no output
  if (v0 >= VOCAB) return;

  // epilogue: LDS transpose -> 256B-contiguous NON-TEMPORAL dword stores
  float* tile = (float*)smem;                // 32x132 f32 = 16.9 KB
  float bo[4];
#pragma unroll
  for (int ni = 0; ni < 4; ++ni) {
    int v = v0 + wn + ni * 16 + l15;
    bo[ni] = (v < VOCAB) ? b_out[v] : 0.0f;
  }
  const int lrow = (wv & 1) * 16 + 4 * lg;
  const int lcol = (wv >> 1) * 64 + l15;
  for (int mi = 0; mi < 4; ++mi) {
    __syncthreads();
#pragma unroll
    for (int ni = 0; ni < 4; ++ni)
#pragma unroll
      for (int rr = 0; rr < 4; ++rr)
        tile[(lrow + rr) * 132 + lcol + ni * 16] = acc[mi][ni][rr] + bo[ni];
    __syncthreads();
#pragma unroll
    for (int j = 0; j < 16; ++j) {
      int eid = j * 256 + tid;
      int lr  = eid >> 7;                     // 0..31
      int c   = eid & 127;
      int ra  = m0 + (lr >> 4) * 64 + mi * 16 + (lr & 15);   // A row = t_out*32+b
      int orow = (ra & 31) * 64 + (ra >> 5);                 // out row = b*64+t_out
      int v = v0 + c;
      if (v < VOCAB)
        st_nt(&out[(size_t)orow * VOCAB + v], tile[lr * 132 + c]);
    }
  }
}

// ---------------------------------------------------------------------------
// host
// ---------------------------------------------------------------------------
extern "C" void kernel_launch(void* const* d_in, const int* in_sizes, int n_in,
                              void* d_out, int out_size, void* d_ws, size_t ws_size,
                              hipStream_t stream) {
  const float* features = (const float*)d_in[0];
  const int*   captions = (const int*)d_in[1];
  const float* embed_w  = (const float*)d_in[2];
  const float* w_ih0    = (const float*)d_in[3];
  const float* w_hh0    = (const float*)d_in[4];
  const float* b0       = (const float*)d_in[5];
  const float* w_ih1    = (const float*)d_in[6];
  const float* w_hh1    = (const float*)d_in[7];
  const float* b1       = (const float*)d_in[8];
  const float* w_out    = (const float*)d_in[9];
  const float* b_out    = (const float*)d_in[10];
  float* out = (float*)d_out;

  char* ws = (char*)d_ws;
  size_t off = 0;
  auto alloc = [&](size_t bytes) -> void* {
    void* p = ws + off;
    off = (off + bytes + 255) & ~(size_t)255;
    return p;
  };
  unsigned* slots = (unsigned*)alloc(64 * 16 * sizeof(unsigned));
  u16* inputs_bf = (u16*)alloc((size_t)NSTEP * BATCH * EMB * 2);
  u16* wih0_bf   = (u16*)alloc((size_t)4 * HID * EMB * 2);
  u16* whh0_bf   = (u16*)alloc((size_t)4 * HID * HID * 2);
  u16* wih1_bf   = (u16*)alloc((size_t)4 * HID * HID * 2);
  u16* whh1_bf   = (u16*)alloc((size_t)4 * HID * HID * 2);
  u16* wout_bf   = (u16*)alloc((size_t)VPADG * HID * 2);
  u16* h0_all    = (u16*)alloc((size_t)NSTEP * BATCH * HID * 2);
  u16* h1_all    = (u16*)alloc((size_t)NSTEP * BATCH * HID * 2);
  (void)ws_size; (void)in_sizes; (void)n_in; (void)out_size;

  hipMemsetAsync(slots, 0, 64 * 16 * sizeof(unsigned), stream);

  {
    int n = NSTEP * BATCH * EMB;
    build_inputs<<<(n + 255) / 256, 256, 0, stream>>>(features, captions, embed_w, inputs_bf);
  }
  {
    int n4 = 4 * HID * EMB / 4;
    cast_bf16<<<(n4 + 255) / 256, 256, 0, stream>>>(w_ih0, wih0_bf, n4);
    cast_bf16<<<(n4 + 255) / 256, 256, 0, stream>>>(w_hh0, whh0_bf, n4);
    cast_bf16<<<(n4 + 255) / 256, 256, 0, stream>>>(w_ih1, wih1_bf, n4);
    cast_bf16<<<(n4 + 255) / 256, 256, 0, stream>>>(w_hh1, whh1_bf, n4);
  }
  {
    int n4 = VPADG * 512 / 4;
    cast_pad_wout<<<(n4 + 255) / 256, 256, 0, stream>>>(w_out, wout_bf);
  }
  // fused: 64 LSTM blocks (dispatched first) + 6400 GEMM tile blocks
  fused_lstm_logits<<<NWG_LSTM + MT_TILES * NT_TILES, 256, 0, stream>>>(
      inputs_bf, wih0_bf, whh0_bf, b0, wih1_bf, whh1_bf, b1,
      h0_all, h1_all, wout_bf, b_out, out, slots);
}

// Round 17
// 435.068 us; speedup vs baseline: 1.1523x; 1.1523x over previous
//
#include <hip/hip_runtime.h>
#include <stdint.h>
#include <math.h>

// ---------------------------------------------------------------------------
// DecoderRNN: 2-layer LSTM (B=32, T=64, E=H=512) + vocab projection (V=50257)
//
//   FUSED kernel: blocks 0..63  = split-K persistent LSTM (round-9 structure)
//                 blocks 64..   = logits-GEMM tiles (128x128xBK64), poll-gated
//                 on h1 readiness; row (b,t) uses h1[t+1].
//   Round-17: r15 base (443us best) + SCOPED s_setprio in the LSTM branch:
//   prio 1 only around MFMA clusters and pointwise+h-store (win CU issue
//   arbitration vs GEMM co-residents during compute bursts), prio 0 during
//   polls/waits/drains (r16's regression was spinning at prio 1).
// ---------------------------------------------------------------------------

typedef unsigned short u16;
typedef __bf16 bf16x8 __attribute__((ext_vector_type(8)));
typedef float  f32x4  __attribute__((ext_vector_type(4)));

#define BATCH   32
#define SEQT    64
#define NSTEP   65
#define EMB     512
#define HID     512
#define VOCAB   50257
#define VPADG   51200         // 400*128, zero-padded
#define NWG_LSTM 64
#define NT_TILES 400
#define MT_TILES 16           // 2048/128

static __device__ __forceinline__ u16 f2bf(float f) {
  unsigned u = __float_as_uint(f);
  u += 0x7FFFu + ((u >> 16) & 1u);
  return (u16)(u >> 16);
}

static __device__ __forceinline__ bf16x8 ld_frag(const u16* p16) {
  union { uint4 u; bf16x8 v; } f;
  f.u = *(const uint4*)p16;
  return f.v;
}

// asm 16B loads: result valid only after manual s_waitcnt vmcnt + sched_barrier.
static __device__ __forceinline__ void gload16(uint4* dst, const void* p) {
  asm volatile("global_load_dwordx4 %0, %1, off" : "=v"(*dst) : "v"(p));
}
static __device__ __forceinline__ void gload16_sys(uint4* dst, const void* p) {
  asm volatile("global_load_dwordx4 %0, %1, off sc0 sc1" : "=v"(*dst) : "v"(p));
}
static __device__ __forceinline__ void st_exch32(void* p, unsigned v) {
  (void)__hip_atomic_exchange((unsigned*)p, v, __ATOMIC_RELAXED,
                              __HIP_MEMORY_SCOPE_AGENT);
}
// non-temporal f32 store (output is write-once, never read)
static __device__ __forceinline__ void st_nt(float* p, float v) {
  asm volatile("global_store_dword %0, %1, off nt" :: "v"(p), "v"(v) : "memory");
}

static __device__ __forceinline__ float sigmoid_fast(float x) {
  return 1.0f / (1.0f + __expf(-x));
}
static __device__ __forceinline__ float tanh_fast(float x) {
  return 1.0f - 2.0f / (__expf(2.0f * x) + 1.0f);
}

// LSTM poll: latency-critical, tight loop (runs at prio 0)
static __device__ __forceinline__ void wave_poll(const unsigned* slots,
                                                 int base_slot, unsigned tgt,
                                                 int lane) {
  const unsigned* p = slots + (base_slot + (lane & 31)) * 16;
  for (;;) {
    unsigned v = __hip_atomic_load(p, __ATOMIC_RELAXED, __HIP_MEMORY_SCOPE_AGENT);
    if (__all((int)(v >= tgt))) break;
    __builtin_amdgcn_s_sleep(1);
  }
}

// GEMM poll: throughput-path, coarse backoff
static __device__ __forceinline__ void wave_poll_slow(const unsigned* slots,
                                                      int base_slot, unsigned tgt,
                                                      int lane) {
  const unsigned* p = slots + (base_slot + (lane & 31)) * 16;
  for (;;) {
    unsigned v = __hip_atomic_load(p, __ATOMIC_RELAXED, __HIP_MEMORY_SCOPE_AGENT);
    if (__all((int)(v >= tgt))) break;
    __builtin_amdgcn_s_sleep(32);
  }
}

#define WAITVM(N) do { asm volatile("s_waitcnt vmcnt(" #N ")" ::: "memory"); \
                       __builtin_amdgcn_sched_barrier(0); } while (0)

// ---------------------------------------------------------------------------
// K1: compact layout dst[t][e>>4][b][e&15]
// ---------------------------------------------------------------------------
__global__ void build_inputs(const float* __restrict__ features,
                             const int*   __restrict__ captions,
                             const float* __restrict__ embed_w,
                             u16* __restrict__ dst) {
  int idx = blockIdx.x * blockDim.x + threadIdx.x;
  const int n = NSTEP * BATCH * EMB;
  if (idx >= n) return;
  int e = idx & (EMB - 1);
  int rem = idx >> 9;
  int b = rem & (BATCH - 1);
  int t = rem >> 5;
  float v;
  if (t == 0) v = features[b * EMB + e];
  else        v = embed_w[(size_t)captions[b * SEQT + (t - 1)] * EMB + e];
  dst[(size_t)t * 16384 + (e >> 4) * 512 + b * 16 + (e & 15)] = f2bf(v);
}

// ---------------------------------------------------------------------------
// K2
// ---------------------------------------------------------------------------
__global__ void cast_bf16(const float* __restrict__ src, u16* __restrict__ dst, int n4) {
  int i = blockIdx.x * blockDim.x + threadIdx.x;
  if (i >= n4) return;
  float4 v = ((const float4*)src)[i];
  ushort4 o;
  o.x = f2bf(v.x); o.y = f2bf(v.y); o.z = f2bf(v.z); o.w = f2bf(v.w);
  ((ushort4*)dst)[i] = o;
}

__global__ void cast_pad_wout(const float* __restrict__ src, u16* __restrict__ dst) {
  int i = blockIdx.x * blockDim.x + threadIdx.x;
  const int n4 = VPADG * 512 / 4;
  const int nsrc4 = VOCAB * 512 / 4;
  if (i >= n4) return;
  ushort4 o;
  if (i < nsrc4) {
    float4 v = ((const float4*)src)[i];
    o.x = f2bf(v.x); o.y = f2bf(v.y); o.z = f2bf(v.z); o.w = f2bf(v.w);
  } else {
    o.x = 0; o.y = 0; o.z = 0; o.w = 0;
  }
  ((ushort4*)dst)[i] = o;
}

// ---------------------------------------------------------------------------
// FUSED kernel
// ---------------------------------------------------------------------------
__global__ __launch_bounds__(256, 1)
void fused_lstm_logits(const u16* __restrict__ inputs_bf,   // [t][32sl][32b][16]
                       const u16* __restrict__ wih0, const u16* __restrict__ whh0,
                       const float* __restrict__ b0,
                       const u16* __restrict__ wih1, const u16* __restrict__ whh1,
                       const float* __restrict__ b1,
                       u16* h0_all, u16* h1_all,             // [t][32sl][32b][16]
                       const u16* __restrict__ Bg,           // w_out bf16 [51200][512]
                       const float* __restrict__ b_out,
                       float* __restrict__ out,
                       unsigned* slots) {
  __shared__ char smem[49408];
  const int tid  = threadIdx.x;
  const int lane = tid & 63;
  const int wv   = tid >> 6;
  const int l15  = lane & 15;
  const int lg   = lane >> 4;

  if (blockIdx.x < NWG_LSTM) {
    // =================== LSTM part (round-9 structure) ===================
    const int wg    = blockIdx.x;
    const int layer = wg >> 5;
    const int jsl   = wg & 31;
    const int j0    = jsl * 16;
    const bool is_h = (wv >= 2);
    const int  wq   = wv & 1;

    const u16*   wih  = layer ? wih1 : wih0;
    const u16*   whh  = layer ? whh1 : whh0;
    const float* bias = layer ? b1 : b0;
    const char* xsrc0 = (const char*)(layer ? h0_all : inputs_bf);
    const char* hsrc0 = (const char*)(layer ? h1_all : h0_all);
    u16*        hdst  = layer ? h1_all : h0_all;
    const int own_base = layer ? 32 : 0;

    float* gparts = (float*)smem;              // [w][g][512] = 32 KB
    float* bias_l = (float*)(smem + 49152);    // [64]

    if (tid < 64) bias_l[tid] = bias[(tid >> 4) * HID + j0 + (tid & 15)];

    uint4 wreg[8][4];
    {
      const u16* wmat = is_h ? whh : wih;
      const int  kb   = wq * 256;
#pragma unroll
      for (int kc = 0; kc < 8; ++kc) {
#pragma unroll
        for (int g4 = 0; g4 < 4; ++g4) {
          gload16(&wreg[kc][g4],
                  wmat + (size_t)(g4 * 512 + j0 + l15) * 512 + kb + kc * 32 + 8 * lg);
        }
        WAITVM(0);
      }
    }
    __syncthreads();

    const int laoff = wq * 16384 + (lg >> 1) * 1024 + l15 * 32 + (lg & 1) * 16;
    const int pw_b  = tid >> 3;
    const int pw_jq = (tid * 2) & 15;
    float creg[2] = {0.f, 0.f};

    for (int t = 0; t < NSTEP; ++t) {
      f32x4 acc[2][4];
#pragma unroll
      for (int bh = 0; bh < 2; ++bh)
#pragma unroll
        for (int g4 = 0; g4 < 4; ++g4) acc[bh][g4] = (f32x4){0.f, 0.f, 0.f, 0.f};

      const bool have_a = is_h ? (t > 0) : true;
      if (have_a) {
        const char* src;
        bool sys;
        if (!is_h) {
          src = xsrc0 + (size_t)t * 32768;
          sys = (layer == 1);
          if (layer == 1) wave_poll(slots, 0, (unsigned)(t + 1), lane);
        } else {
          src = hsrc0 + (size_t)(t - 1) * 32768;
          sys = true;
          wave_poll(slots, own_base, (unsigned)t, lane);
        }
        uint4 areg[2][8];
        if (sys) {
#pragma unroll
          for (int kc = 0; kc < 8; ++kc) gload16_sys(&areg[0][kc], src + laoff + kc * 2048);
#pragma unroll
          for (int kc = 0; kc < 8; ++kc) gload16_sys(&areg[1][kc], src + laoff + kc * 2048 + 512);
        } else {
#pragma unroll
          for (int kc = 0; kc < 8; ++kc) gload16(&areg[0][kc], src + laoff + kc * 2048);
#pragma unroll
          for (int kc = 0; kc < 8; ++kc) gload16(&areg[1][kc], src + laoff + kc * 2048 + 512);
        }
        WAITVM(8);
        __builtin_amdgcn_s_setprio(1);       // compute burst: win arbitration
#pragma unroll
        for (int kc = 0; kc < 8; ++kc)
#pragma unroll
          for (int g4 = 0; g4 < 4; ++g4)
            acc[0][g4] = __builtin_amdgcn_mfma_f32_16x16x32_bf16(
                *(const bf16x8*)&areg[0][kc], *(const bf16x8*)&wreg[kc][g4],
                acc[0][g4], 0, 0, 0);
        WAITVM(0);
#pragma unroll
        for (int kc = 0; kc < 8; ++kc)
#pragma unroll
          for (int g4 = 0; g4 < 4; ++g4)
            acc[1][g4] = __builtin_amdgcn_mfma_f32_16x16x32_bf16(
                *(const bf16x8*)&areg[1][kc], *(const bf16x8*)&wreg[kc][g4],
                acc[1][g4], 0, 0, 0);
        __builtin_amdgcn_s_setprio(0);
      }
#pragma unroll
      for (int bh = 0; bh < 2; ++bh)
#pragma unroll
        for (int g4 = 0; g4 < 4; ++g4)
#pragma unroll
          for (int rr = 0; rr < 4; ++rr)
            gparts[(wv * 4 + g4) * 512 + (bh * 16 + 4 * lg + rr) * 16 + l15] = acc[bh][g4][rr];
      __syncthreads();

      {
        __builtin_amdgcn_s_setprio(1);       // pointwise + h-store burst
        const int b = pw_b, jq = pw_jq;
        float hv[2];
#pragma unroll
        for (int u = 0; u < 2; ++u) {
          const int jj = jq + u;
          float gi = bias_l[0 * 16 + jj];
          float gf = bias_l[1 * 16 + jj];
          float gg = bias_l[2 * 16 + jj];
          float go = bias_l[3 * 16 + jj];
#pragma unroll
          for (int w = 0; w < 4; ++w) {
            gi += gparts[(w * 4 + 0) * 512 + b * 16 + jj];
            gf += gparts[(w * 4 + 1) * 512 + b * 16 + jj];
            gg += gparts[(w * 4 + 2) * 512 + b * 16 + jj];
            go += gparts[(w * 4 + 3) * 512 + b * 16 + jj];
          }
          float cn = sigmoid_fast(gf) * creg[u] + sigmoid_fast(gi) * tanh_fast(gg);
          creg[u] = cn;
          hv[u] = sigmoid_fast(go) * tanh_fast(cn);
        }
        unsigned pk32 = (unsigned)f2bf(hv[0]) | ((unsigned)f2bf(hv[1]) << 16);
        st_exch32((char*)hdst + (size_t)t * 32768 + jsl * 1024 + b * 32 + jq * 2, pk32);
        __builtin_amdgcn_s_setprio(0);       // drain/signal at normal prio
      }
      asm volatile("s_waitcnt vmcnt(0)" ::: "memory");   // drain h exchange (L3 ack)
      __syncthreads();
      if (tid == 0)
        (void)__hip_atomic_exchange(&slots[wg * 16], (unsigned)(t + 1),
                                    __ATOMIC_RELAXED, __HIP_MEMORY_SCOPE_AGENT);
    }
    return;
  }

  // =================== GEMM tile part (128x128, no-spill, r15) =============
  // out row (b, t_out) uses h1[t_out + 1]; A row ra = t_out*32 + b.
  const int g  = blockIdx.x - NWG_LSTM;
  const int mt = g / NT_TILES;               // 0..15, readiness-ordered
  const int nt = g - mt * NT_TILES;          // 0..399
  const int m0 = mt * 128, v0 = nt * 128;
  const int wm = (wv & 1) * 64;
  const int wn = (wv >> 1) * 64;

  u16* As = (u16*)smem;                      // 16 KB
  u16* Bs = (u16*)(smem + 16384);            // 16 KB
  const char* h1c = (const char*)h1_all;

  f32x4 acc[4][4];
#pragma unroll
  for (int mi = 0; mi < 4; ++mi)
#pragma unroll
    for (int ni = 0; ni < 4; ++ni)
      acc[mi][ni] = (f32x4){0.f, 0.f, 0.f, 0.f};

  const int rswz = (l15 & 7) << 3;

  // need h1[t_h], t_h in [mt*4+1, mt*4+4] -> all 32 L1 slots >= mt*4+5
  if (tid < 64) wave_poll_slow(slots, 32, (unsigned)(mt * 4 + 5), lane);
  __syncthreads();

  for (int kt = 0; kt < 8; ++kt) {
    // A: plain global_load_lds from h1_all, pre-swizzled source (rule #21)
#pragma unroll
    for (int c = 0; c < 4; ++c) {
      int chunk = wv * 256 + c * 64 + lane;   // 0..1023
      int row   = chunk >> 3;                 // 0..127
      int kc3   = (chunk & 7) ^ (row & 7);
      int gkc   = kt * 8 + kc3;               // global 16B-chunk 0..63
      int ra    = m0 + row;                   // t_out = ra>>5, b = ra&31
      const char* pa = h1c + (size_t)((ra >> 5) + 1) * 32768 + (gkc >> 1) * 1024 +
                       (ra & 31) * 32 + (gkc & 1) * 16;
      u16* la = &As[(wv * 256 + c * 64) * 8];
      __builtin_amdgcn_global_load_lds(
          (const __attribute__((address_space(1))) void*)pa,
          (__attribute__((address_space(3))) void*)la, 16, 0, 0);
    }
    // B: global_load_lds, pre-swizzled source
#pragma unroll
    for (int c = 0; c < 4; ++c) {
      int chunk = wv * 256 + c * 64 + lane;
      int row   = chunk >> 3;
      int kcs   = ((chunk & 7) ^ (row & 7)) << 3;
      const u16* gb = Bg + (size_t)(v0 + row) * 512 + kt * 64 + kcs;
      u16* lb = &Bs[(wv * 256 + c * 64) * 8];
      __builtin_amdgcn_global_load_lds(
          (const __attribute__((address_space(1))) void*)gb,
          (__attribute__((address_space(3))) void*)lb, 16, 0, 0);
    }
    WAITVM(0);
    __syncthreads();

#pragma unroll
    for (int ks = 0; ks < 2; ++ks) {
      bf16x8 af[4], bfr[4];
#pragma unroll
      for (int i = 0; i < 4; ++i) {
        af[i]  = ld_frag(&As[(wm + i * 16 + l15) * 64 + ((ks * 32 + 8 * lg) ^ rswz)]);
        bfr[i] = ld_frag(&Bs[(wn + i * 16 + l15) * 64 + ((ks * 32 + 8 * lg) ^ rswz)]);
      }
#pragma unroll
      for (int mi = 0; mi < 4; ++mi)
#pragma unroll
        for (int ni = 0; ni < 4; ++ni)
          acc[mi][ni] = __builtin_amdgcn_mfma_f32_16x16x32_bf16(
              af[mi], bfr[ni], acc[mi][ni], 0, 0, 0);
    }
    __syncthreads();
  }

  // all-padded tiles (v0 >= VOCAB) produce no output
  if (v0 >= VOCAB) return;

  // epilogue: LDS transpose -> 256B-contiguous NON-TEMPORAL dword stores
  float* tile = (float*)smem;                // 32x132 f32 = 16.9 KB
  float bo[4];
#pragma unroll
  for (int ni = 0; ni < 4; ++ni) {
    int v = v0 + wn + ni * 16 + l15;
    bo[ni] = (v < VOCAB) ? b_out[v] : 0.0f;
  }
  const int lrow = (wv & 1) * 16 + 4 * lg;
  const int lcol = (wv >> 1) * 64 + l15;
  for (int mi = 0; mi < 4; ++mi) {
    __syncthreads();
#pragma unroll
    for (int ni = 0; ni < 4; ++ni)
#pragma unroll
      for (int rr = 0; rr < 4; ++rr)
        tile[(lrow + rr) * 132 + lcol + ni * 16] = acc[mi][ni][rr] + bo[ni];
    __syncthreads();
#pragma unroll
    for (int j = 0; j < 16; ++j) {
      int eid = j * 256 + tid;
      int lr  = eid >> 7;                     // 0..31
      int c   = eid & 127;
      int ra  = m0 + (lr >> 4) * 64 + mi * 16 + (lr & 15);   // A row = t_out*32+b
      int orow = (ra & 31) * 64 + (ra >> 5);                 // out row = b*64+t_out
      int v = v0 + c;
      if (v < VOCAB)
        st_nt(&out[(size_t)orow * VOCAB + v], tile[lr * 132 + c]);
    }
  }
}

// ---------------------------------------------------------------------------
// host
// ---------------------------------------------------------------------------
extern "C" void kernel_launch(void* const* d_in, const int* in_sizes, int n_in,
                              void* d_out, int out_size, void* d_ws, size_t ws_size,
                              hipStream_t stream) {
  const float* features = (const float*)d_in[0];
  const int*   captions = (const int*)d_in[1];
  const float* embed_w  = (const float*)d_in[2];
  const float* w_ih0    = (const float*)d_in[3];
  const float* w_hh0    = (const float*)d_in[4];
  const float* b0       = (const float*)d_in[5];
  const float* w_ih1    = (const float*)d_in[6];
  const float* w_hh1    = (const float*)d_in[7];
  const float* b1       = (const float*)d_in[8];
  const float* w_out    = (const float*)d_in[9];
  const float* b_out    = (const float*)d_in[10];
  float* out = (float*)d_out;

  char* ws = (char*)d_ws;
  size_t off = 0;
  auto alloc = [&](size_t bytes) -> void* {
    void* p = ws + off;
    off = (off + bytes + 255) & ~(size_t)255;
    return p;
  };
  unsigned* slots = (unsigned*)alloc(64 * 16 * sizeof(unsigned));
  u16* inputs_bf = (u16*)alloc((size_t)NSTEP * BATCH * EMB * 2);
  u16* wih0_bf   = (u16*)alloc((size_t)4 * HID * EMB * 2);
  u16* whh0_bf   = (u16*)alloc((size_t)4 * HID * HID * 2);
  u16* wih1_bf   = (u16*)alloc((size_t)4 * HID * HID * 2);
  u16* whh1_bf   = (u16*)alloc((size_t)4 * HID * HID * 2);
  u16* wout_bf   = (u16*)alloc((size_t)VPADG * HID * 2);
  u16* h0_all    = (u16*)alloc((size_t)NSTEP * BATCH * HID * 2);
  u16* h1_all    = (u16*)alloc((size_t)NSTEP * BATCH * HID * 2);
  (void)ws_size; (void)in_sizes; (void)n_in; (void)out_size;

  hipMemsetAsync(slots, 0, 64 * 16 * sizeof(unsigned), stream);

  {
    int n = NSTEP * BATCH * EMB;
    build_inputs<<<(n + 255) / 256, 256, 0, stream>>>(features, captions, embed_w, inputs_bf);
  }
  {
    int n4 = 4 * HID * EMB / 4;
    cast_bf16<<<(n4 + 255) / 256, 256, 0, stream>>>(w_ih0, wih0_bf, n4);
    cast_bf16<<<(n4 + 255) / 256, 256, 0, stream>>>(w_hh0, whh0_bf, n4);
    cast_bf16<<<(n4 + 255) / 256, 256, 0, stream>>>(w_ih1, wih1_bf, n4);
    cast_bf16<<<(n4 + 255) / 256, 256, 0, stream>>>(w_hh1, whh1_bf, n4);
  }
  {
    int n4 = VPADG * 512 / 4;
    cast_pad_wout<<<(n4 + 255) / 256, 256, 0, stream>>>(w_out, wout_bf);
  }
  // fused: 64 LSTM blocks (dispatched first) + 6400 GEMM tile blocks
  fused_lstm_logits<<<NWG_LSTM + MT_TILES * NT_TILES, 256, 0, stream>>>(
      inputs_bf, wih0_bf, whh0_bf, b0, wih1_bf, whh1_bf, b1,
      h0_all, h1_all, wout_bf, b_out, out, slots);
}